// Round 1
// baseline (64.476 us; speedup 1.0000x reference)
//
#include <hip/hip_runtime.h>

// Until_15753940041804: soft "until" operator.
// best[b,t,c] = log( sum_{k=0..K-1} 1/(S_k + exp(-s*psi[b,t+k,c])) ) / s
//   where S_0 = exp(-s*1.0),  S_k = sum_{j<k} exp(-s*phi[b,t+j,c])  (k>=1),
//   K = min(64, T - t).  Invalid k contribute exp(-s*10000) == 0 in fp32.
// Derived by exponentiating the reference's logaddexp/cumlse chain; all
// magnitudes stay within e^{+-45} for N(0,1) inputs, fp32-safe.

#define T_DIM   2048
#define W_WIN   64
#define BLOCK_T 256

__global__ __launch_bounds__(BLOCK_T) void until_kernel(
    const float* __restrict__ phi,
    const float* __restrict__ psi,
    const int*  __restrict__ scale_p,
    float* __restrict__ out)
{
    __shared__ float2 s_phi[BLOCK_T + W_WIN - 1];
    __shared__ float2 s_psi[BLOCK_T + W_WIN - 1];

    const int b   = blockIdx.y;
    const int t0  = blockIdx.x * BLOCK_T;
    const int tid = threadIdx.x;
    const float s = (float)(*scale_p);

    const float2* __restrict__ phi2 = (const float2*)(phi + (size_t)b * T_DIM * 2);
    const float2* __restrict__ psi2 = (const float2*)(psi + (size_t)b * T_DIM * 2);

    // Stage phi/psi windows into LDS (coalesced float2 loads).
    for (int i = tid; i < BLOCK_T + W_WIN - 1; i += BLOCK_T) {
        int t = t0 + i;
        float2 pv = make_float2(0.f, 0.f);
        float2 qv = make_float2(0.f, 0.f);
        if (t < T_DIM) { pv = phi2[t]; qv = psi2[t]; }
        s_phi[i] = pv;
        s_psi[i] = qv;
    }
    __syncthreads();

    const int t = t0 + tid;          // always < T_DIM (grid exact)
    const int K = min(W_WIN, T_DIM - t);
    const float Es = __expf(-s);     // exp(-s * 1.0) — the k==0 "min_phi = 1.0" branch

    // k = 0
    float2 q0 = s_psi[tid];
    float acc0 = __builtin_amdgcn_rcpf(Es + __expf(-s * q0.x));
    float acc1 = __builtin_amdgcn_rcpf(Es + __expf(-s * q0.y));
    float2 p0 = s_phi[tid];
    float sum0 = __expf(-s * p0.x);
    float sum1 = __expf(-s * p0.y);

    #pragma unroll 7
    for (int k = 1; k < K; ++k) {
        float2 pp = s_phi[tid + k];
        float2 qq = s_psi[tid + k];
        acc0 += __builtin_amdgcn_rcpf(sum0 + __expf(-s * qq.x));
        acc1 += __builtin_amdgcn_rcpf(sum1 + __expf(-s * qq.y));
        sum0 += __expf(-s * pp.x);
        sum1 += __expf(-s * pp.y);
    }

    float2* __restrict__ out2 = (float2*)(out + (size_t)b * T_DIM * 2);
    out2[t] = make_float2(__logf(acc0) / s, __logf(acc1) / s);
}

extern "C" void kernel_launch(void* const* d_in, const int* in_sizes, int n_in,
                              void* d_out, int out_size, void* d_ws, size_t ws_size,
                              hipStream_t stream) {
    const float* phi   = (const float*)d_in[0];
    const float* psi   = (const float*)d_in[1];
    const int*   scale = (const int*)d_in[2];
    float* out = (float*)d_out;

    const int B = in_sizes[0] / (T_DIM * 2);   // 64
    dim3 grid(T_DIM / BLOCK_T, B);             // (8, 64) = 512 blocks
    until_kernel<<<grid, dim3(BLOCK_T), 0, stream>>>(phi, psi, scale, out);
}

// Round 2
// 61.457 us; speedup vs baseline: 1.0491x; 1.0491x over previous
//
#include <hip/hip_runtime.h>
#include <math.h>

// Until_15753940041804: soft "until" operator.
// best[b,t,c] = log( sum_{k=0..63} 1/(S_k + exp(-s*psi[b,t+k,c])) ) / s
//   S_0 = exp(-s*1.0),  S_k = sum_{j<k} exp(-s*phi[b,t+j,c])  (k>=1).
// Reference pads phi with +1e4 (=> exp term 0) and psi with -1e4 (=> exp term
// +inf => rcp -> 0), so staging ep=0 / eq=+inf past T reproduces padding and
// the 'valid' mask exactly, letting the k-loop run a constant 64 iterations.
//
// R2 change vs R1: exponentials hoisted out of the inner loop — each element
// is exp'd ONCE at staging (319/block) instead of 64x (16384/block). Inner
// loop: 1 ds_read_b128 + 2 v_rcp + 6 adds. Full unroll (const trip count),
// split accumulators to break the serial acc chain.

#define T_DIM   2048
#define W_WIN   64
#define BLOCK_T 256
#define STAGE   (BLOCK_T + W_WIN - 1)   // 319

__global__ __launch_bounds__(BLOCK_T) void until_kernel(
    const float* __restrict__ phi,
    const float* __restrict__ psi,
    const int*  __restrict__ scale_p,
    float* __restrict__ out)
{
    // x = ep ch0, y = ep ch1, z = eq ch0, w = eq ch1
    __shared__ float4 s_d[STAGE];

    const int b   = blockIdx.y;
    const int t0  = blockIdx.x * BLOCK_T;
    const int tid = threadIdx.x;
    const float s  = (float)(*scale_p);
    const float ns = -s;

    const float2* __restrict__ phi2 = (const float2*)(phi + (size_t)b * T_DIM * 2);
    const float2* __restrict__ psi2 = (const float2*)(psi + (size_t)b * T_DIM * 2);

    // Stage: exp once per element. Past T: ep=0 (phi pad +1e4), eq=+inf (psi pad -1e4).
    for (int i = tid; i < STAGE; i += BLOCK_T) {
        int t = t0 + i;
        float4 v;
        if (t < T_DIM) {
            float2 pv = phi2[t];
            float2 qv = psi2[t];
            v.x = __expf(ns * pv.x);
            v.y = __expf(ns * pv.y);
            v.z = __expf(ns * qv.x);
            v.w = __expf(ns * qv.y);
        } else {
            v.x = 0.f; v.y = 0.f;
            v.z = INFINITY; v.w = INFINITY;
        }
        s_d[i] = v;
    }
    __syncthreads();

    const float Es = __expf(ns);   // k==0 term: min_phi forced to 1.0

    // k = 0
    float4 v0 = s_d[tid];
    float accA0 = __builtin_amdgcn_rcpf(Es + v0.z);
    float accA1 = __builtin_amdgcn_rcpf(Es + v0.w);
    float accB0 = 0.f, accB1 = 0.f;
    float sum0 = v0.x;
    float sum1 = v0.y;

    #pragma unroll
    for (int k = 1; k < W_WIN; ++k) {
        float4 v = s_d[tid + k];
        float r0 = __builtin_amdgcn_rcpf(sum0 + v.z);
        float r1 = __builtin_amdgcn_rcpf(sum1 + v.w);
        if (k & 1) { accA0 += r0; accA1 += r1; }
        else       { accB0 += r0; accB1 += r1; }
        sum0 += v.x;
        sum1 += v.y;
    }

    const int t = t0 + tid;
    float2* __restrict__ out2 = (float2*)(out + (size_t)b * T_DIM * 2);
    out2[t] = make_float2(__logf(accA0 + accB0) / s, __logf(accA1 + accB1) / s);
}

extern "C" void kernel_launch(void* const* d_in, const int* in_sizes, int n_in,
                              void* d_out, int out_size, void* d_ws, size_t ws_size,
                              hipStream_t stream) {
    const float* phi   = (const float*)d_in[0];
    const float* psi   = (const float*)d_in[1];
    const int*   scale = (const int*)d_in[2];
    float* out = (float*)d_out;

    const int B = in_sizes[0] / (T_DIM * 2);   // 64
    dim3 grid(T_DIM / BLOCK_T, B);             // (8, 64) = 512 blocks
    until_kernel<<<grid, dim3(BLOCK_T), 0, stream>>>(phi, psi, scale, out);
}